// Round 2
// baseline (625.873 us; speedup 1.0000x reference)
//
#include <hip/hip_runtime.h>
#include <stdint.h>

#define NLEV 16
#define LOG2_T 19
#define TMASK ((1u << LOG2_T) - 1u)
#define P1 2654435761u
#define P2 805459861u

typedef float floatx4 __attribute__((ext_vector_type(4)));
typedef float floatx2 __attribute__((ext_vector_type(2)));

#define PTS1 4
#define BLOCK1 256
#define CHUNK1 (BLOCK1 * PTS1)   // 1024 points per block

// ---- shared helper: one point, one level (exact fp32 to match numpy ref) ----
__device__ __forceinline__ floatx2 encode_point_level(
    float xn, float yn, float zn, float res,
    const floatx2* __restrict__ tbl)
{
    const float posx = xn * res;
    const float posy = yn * res;
    const float posz = zn * res;
    const float flx = floorf(posx);
    const float fly = floorf(posy);
    const float flz = floorf(posz);
    const float fx = posx - flx, fy = posy - fly, fz = posz - flz;
    const int ix = (int)flx, iy = (int)fly, iz = (int)flz;

    const uint32_t hx0 = (uint32_t)ix;
    const uint32_t hx1 = (uint32_t)(ix + 1);
    const uint32_t hy0 = (uint32_t)iy * P1;
    const uint32_t hy1 = (uint32_t)(iy + 1) * P1;
    const uint32_t hz0 = (uint32_t)iz * P2;
    const uint32_t hz1 = (uint32_t)(iz + 1) * P2;

    uint32_t idx[8];
    idx[0] = (hx0 ^ hy0 ^ hz0) & TMASK;
    idx[1] = (hx0 ^ hy0 ^ hz1) & TMASK;
    idx[2] = (hx0 ^ hy1 ^ hz0) & TMASK;
    idx[3] = (hx0 ^ hy1 ^ hz1) & TMASK;
    idx[4] = (hx1 ^ hy0 ^ hz0) & TMASK;
    idx[5] = (hx1 ^ hy0 ^ hz1) & TMASK;
    idx[6] = (hx1 ^ hy1 ^ hz0) & TMASK;
    idx[7] = (hx1 ^ hy1 ^ hz1) & TMASK;

    floatx2 f[8];
    #pragma unroll
    for (int c = 0; c < 8; ++c) f[c] = tbl[idx[c]];

    const float gx = 1.f - fx, gy = 1.f - fy, gz = 1.f - fz;
    const float wx[2] = {gx, fx};
    const float wy[2] = {gy, fy};
    const float wz[2] = {gz, fz};

    float s0 = 0.f, s1 = 0.f;
    #pragma unroll
    for (int c = 0; c < 8; ++c) {
        const float w = (wx[(c >> 2) & 1] * wy[(c >> 1) & 1]) * wz[c & 1];
        s0 = fmaf(w, f[c].x, s0);
        s1 = fmaf(w, f[c].y, s1);
    }
    floatx2 r = {s0, s1};
    return r;
}

// ---- phase 1: one level per XCD (level = base + blockIdx%8), ws[l][N][2] ----
// R2 fix: previous version had VGPR_Count=20 -> compiler serialized one point's
// 8 gathers per vmcnt drain (latency-bound: VALUBusy 8%, hbm 12%, occ 81%,
// ~670 exposed cycles/point/wave). Batch all PTS1*8=32 index computations and
// gather issues BEFORE the FMA reduction so points 1..3's loads stay in flight
// under point 0's math. MLP 8->32 at VGPR ~110 (occ ~4-5 waves/SIMD).
__global__ __launch_bounds__(BLOCK1) void level_kernel(
    const float* __restrict__ x,
    const float* __restrict__ bb,
    const float* __restrict__ table_f,
    float* __restrict__ ws,
    int n, int level_base)
{
    const int level = level_base + (int)(blockIdx.x & 7);
    const int chunk = (int)(blockIdx.x >> 3);
    const int base  = chunk * CHUNK1 + (int)threadIdx.x;

    const float bx0 = bb[0], by0 = bb[1], bz0 = bb[2];
    const float bx1 = bb[3], by1 = bb[4], bz1 = bb[5];

    const float res = (float)(16 << level);      // floor(16*2^l) exact
    const floatx2* __restrict__ tbl =
        (const floatx2*)table_f + ((size_t)level << LOG2_T);
    floatx2* __restrict__ wrow = (floatx2*)ws + (size_t)level * n;

    if (base + (PTS1 - 1) * BLOCK1 < n) {
        // ---- fast path: batch indices, batch gathers, then reduce ----
        float fx[PTS1], fy[PTS1], fz[PTS1];
        uint32_t idx[PTS1][8];

        #pragma unroll
        for (int k = 0; k < PTS1; ++k) {
            const int p = base + k * BLOCK1;
            const float xn = (x[3 * p + 0] - bx0) / (bx1 - bx0);
            const float yn = (x[3 * p + 1] - by0) / (by1 - by0);
            const float zn = (x[3 * p + 2] - bz0) / (bz1 - bz0);
            const float posx = xn * res;
            const float posy = yn * res;
            const float posz = zn * res;
            const float flx = floorf(posx);
            const float fly = floorf(posy);
            const float flz = floorf(posz);
            fx[k] = posx - flx;
            fy[k] = posy - fly;
            fz[k] = posz - flz;
            const int ix = (int)flx, iy = (int)fly, iz = (int)flz;
            const uint32_t hx0 = (uint32_t)ix;
            const uint32_t hx1 = (uint32_t)(ix + 1);
            const uint32_t hy0 = (uint32_t)iy * P1;
            const uint32_t hy1 = (uint32_t)(iy + 1) * P1;
            const uint32_t hz0 = (uint32_t)iz * P2;
            const uint32_t hz1 = (uint32_t)(iz + 1) * P2;
            idx[k][0] = (hx0 ^ hy0 ^ hz0) & TMASK;
            idx[k][1] = (hx0 ^ hy0 ^ hz1) & TMASK;
            idx[k][2] = (hx0 ^ hy1 ^ hz0) & TMASK;
            idx[k][3] = (hx0 ^ hy1 ^ hz1) & TMASK;
            idx[k][4] = (hx1 ^ hy0 ^ hz0) & TMASK;
            idx[k][5] = (hx1 ^ hy0 ^ hz1) & TMASK;
            idx[k][6] = (hx1 ^ hy1 ^ hz0) & TMASK;
            idx[k][7] = (hx1 ^ hy1 ^ hz1) & TMASK;
        }

        floatx2 f[PTS1][8];
        #pragma unroll
        for (int k = 0; k < PTS1; ++k) {
            #pragma unroll
            for (int c = 0; c < 8; ++c) {
                f[k][c] = tbl[idx[k][c]];         // 32 loads in flight
            }
        }

        #pragma unroll
        for (int k = 0; k < PTS1; ++k) {
            const float gx = 1.f - fx[k], gy = 1.f - fy[k], gz = 1.f - fz[k];
            const float wxv[2] = {gx, fx[k]};
            const float wyv[2] = {gy, fy[k]};
            const float wzv[2] = {gz, fz[k]};
            float s0 = 0.f, s1 = 0.f;
            #pragma unroll
            for (int c = 0; c < 8; ++c) {
                const float w = (wxv[(c >> 2) & 1] * wyv[(c >> 1) & 1]) * wzv[c & 1];
                s0 = fmaf(w, f[k][c].x, s0);
                s1 = fmaf(w, f[k][c].y, s1);
            }
            floatx2 r = {s0, s1};
            __builtin_nontemporal_store(r, wrow + (base + k * BLOCK1));
        }
    } else {
        // ---- tail fallback: per-point ----
        for (int k = 0; k < PTS1; ++k) {
            const int p = base + k * BLOCK1;
            if (p >= n) continue;
            const float xn = (x[3 * p + 0] - bx0) / (bx1 - bx0);
            const float yn = (x[3 * p + 1] - by0) / (by1 - by0);
            const float zn = (x[3 * p + 2] - bz0) / (bz1 - bz0);
            floatx2 r = encode_point_level(xn, yn, zn, res, tbl);
            __builtin_nontemporal_store(r, wrow + p);
        }
    }
}

// ---- phase 2: transpose ws[16][N][2] -> enc[N][32] via LDS, compute mask ----
// (R1 win: LDS-staged contiguous stores removed 3x HBM write amplification;
//  transpose now ~25us. Do not revert to per-lane strided NT stores.)
__global__ __launch_bounds__(256) void transpose_kernel(
    const float* __restrict__ ws,
    const float* __restrict__ x,
    const float* __restrict__ bb,
    float* __restrict__ enc_out,
    float* __restrict__ mask_out,
    int n)
{
    __shared__ float tile[256 * 33];

    const int tid = (int)threadIdx.x;
    const int b0  = (int)blockIdx.x * 256;
    const int p   = b0 + tid;

    const floatx2* __restrict__ w = (const floatx2*)ws;

    if (p < n) {
        float* row = tile + tid * 33;
        #pragma unroll
        for (int l = 0; l < NLEV; ++l) {
            floatx2 v = w[(size_t)l * n + p];     // lane-contiguous: coalesced
            row[2 * l + 0] = v.x;
            row[2 * l + 1] = v.y;
        }

        const float bx0 = bb[0], by0 = bb[1], bz0 = bb[2];
        const float bx1 = bb[3], by1 = bb[4], bz1 = bb[5];
        const float xn = (x[3 * p + 0] - bx0) / (bx1 - bx0);
        const float yn = (x[3 * p + 1] - by0) / (by1 - by0);
        const float zn = (x[3 * p + 2] - bz0) / (bz1 - bz0);
        const bool inb = (xn > 0.f) & (xn < 1.f) &
                         (yn > 0.f) & (yn < 1.f) &
                         (zn > 0.f) & (zn < 1.f);
        __builtin_nontemporal_store(inb ? 1.0f : 0.0f, mask_out + p);
    }
    __syncthreads();

    const int npts = (n - b0 < 256) ? (n - b0) : 256;
    floatx4* const eb = (floatx4*)(enc_out + (size_t)b0 * (2 * NLEV));

    if (npts == 256) {
        #pragma unroll
        for (int it = 0; it < 8; ++it) {
            const int c  = it * 256 + tid;        // float4 chunk within block tile
            const int pp = c >> 3;                // point within block
            const int jj = (c & 7) << 2;          // feature word
            const float* s = tile + pp * 33 + jj;
            floatx4 v = { s[0], s[1], s[2], s[3] };
            __builtin_nontemporal_store(v, eb + c);   // lanes contiguous: 1KiB/wave
        }
    } else {
        for (int it = 0; it < 8; ++it) {
            const int c  = it * 256 + tid;
            const int pp = c >> 3;
            if (pp < npts) {
                const int jj = (c & 7) << 2;
                const float* s = tile + pp * 33 + jj;
                floatx4 v = { s[0], s[1], s[2], s[3] };
                __builtin_nontemporal_store(v, eb + c);
            }
        }
    }
}

// ---- fallback: direct single-kernel version (R1, verified correct) ----
__global__ __launch_bounds__(256) void hashenc_direct(
    const float* __restrict__ x,
    const float* __restrict__ bb,
    const float* __restrict__ table_f,
    float* __restrict__ enc_out,
    float* __restrict__ mask_out,
    int n)
{
    const int i = blockIdx.x * 256 + (int)threadIdx.x;
    if (i >= n) return;

    const float bx0 = bb[0], by0 = bb[1], bz0 = bb[2];
    const float bx1 = bb[3], by1 = bb[4], bz1 = bb[5];
    const float xn = (x[3 * i + 0] - bx0) / (bx1 - bx0);
    const float yn = (x[3 * i + 1] - by0) / (by1 - by0);
    const float zn = (x[3 * i + 2] - bz0) / (bz1 - bz0);
    const bool inb = (xn > 0.f) & (xn < 1.f) &
                     (yn > 0.f) & (yn < 1.f) &
                     (zn > 0.f) & (zn < 1.f);

    const floatx2* table = (const floatx2*)table_f;
    float enc[2 * NLEV];
    for (int l = 0; l < NLEV; ++l) {
        const float res = (float)(16 << l);
        floatx2 r = encode_point_level(xn, yn, zn, res,
                                       table + ((size_t)l << LOG2_T));
        enc[2 * l + 0] = r.x;
        enc[2 * l + 1] = r.y;
    }
    floatx4* o = (floatx4*)(enc_out + (size_t)i * (2 * NLEV));
    #pragma unroll
    for (int k = 0; k < (2 * NLEV) / 4; ++k) {
        floatx4 v = { enc[4 * k + 0], enc[4 * k + 1],
                      enc[4 * k + 2], enc[4 * k + 3] };
        __builtin_nontemporal_store(v, o + k);
    }
    __builtin_nontemporal_store(inb ? 1.0f : 0.0f, mask_out + i);
}

extern "C" void kernel_launch(void* const* d_in, const int* in_sizes, int n_in,
                              void* d_out, int out_size, void* d_ws, size_t ws_size,
                              hipStream_t stream) {
    const float* x     = (const float*)d_in[0];
    const float* bb    = (const float*)d_in[1];
    const float* table = (const float*)d_in[2];
    const int n = in_sizes[0] / 3;

    float* enc_out  = (float*)d_out;
    float* mask_out = enc_out + (size_t)n * (2 * NLEV);

    const size_t ws_need = (size_t)NLEV * (size_t)n * 2 * sizeof(float);
    if (ws_size >= ws_need) {
        float* ws = (float*)d_ws;
        const int chunks = (n + CHUNK1 - 1) / CHUNK1;
        const int grid1 = chunks * 8;
        level_kernel<<<grid1, BLOCK1, 0, stream>>>(x, bb, table, ws, n, 0);
        level_kernel<<<grid1, BLOCK1, 0, stream>>>(x, bb, table, ws, n, 8);
        const int grid2 = (n + 255) / 256;
        transpose_kernel<<<grid2, 256, 0, stream>>>(ws, x, bb, enc_out, mask_out, n);
    } else {
        const int grid = (n + 255) / 256;
        hashenc_direct<<<grid, 256, 0, stream>>>(x, bb, table, enc_out, mask_out, n);
    }
}

// Round 3
// 513.083 us; speedup vs baseline: 1.2198x; 1.2198x over previous
//
#include <hip/hip_runtime.h>
#include <stdint.h>

#define NLEV 16
#define LOG2_T 19
#define TMASK ((1u << LOG2_T) - 1u)
#define P1 2654435761u
#define P2 805459861u

typedef float floatx4 __attribute__((ext_vector_type(4)));
typedef float floatx2 __attribute__((ext_vector_type(2)));

#define PTS1 4
#define BLOCK1 256
#define CHUNK1 (BLOCK1 * PTS1)   // 1024 points per block

// ---- one point, one level (exact fp32, same FMA order as reference) ----
// R3: levels are L2 scattered-REQUEST-throughput bound (~11.6 req/cy/XCD;
// R2's 4x MLP increase gave zero gain -> not latency-bound). Reduce request
// count: PRIMES[0]==1 means the two x-corners of each (y,z) combo are
// idx and idx^(x even ? 1 : ...) -- for even x they form one aligned 16B
// table pair, fetched by a single dwordx4. avg requests/point: 8 -> 6.
__device__ __forceinline__ floatx2 encode_point_level(
    float xn, float yn, float zn, float res,
    const float* __restrict__ tbl_f)      // 2 floats per entry
{
    const float posx = xn * res;
    const float posy = yn * res;
    const float posz = zn * res;
    const float flx = floorf(posx);
    const float fly = floorf(posy);
    const float flz = floorf(posz);
    const float fx = posx - flx, fy = posy - fly, fz = posz - flz;
    const int ix = (int)flx, iy = (int)fly, iz = (int)flz;

    const uint32_t ux  = (uint32_t)ix;
    const uint32_t hy0 = (uint32_t)iy * P1;
    const uint32_t hy1 = (uint32_t)(iy + 1) * P1;
    const uint32_t hz0 = (uint32_t)iz * P2;
    const uint32_t hz1 = (uint32_t)(iz + 1) * P2;

    // j: bit1 = y-corner, bit0 = z-corner  (matches ref order c = x*4 + j)
    const uint32_t byz[4] = { hy0 ^ hz0, hy0 ^ hz1, hy1 ^ hz0, hy1 ^ hz1 };

    uint32_t ia[4];
    floatx4  pr[4];
    #pragma unroll
    for (int j = 0; j < 4; ++j) {
        ia[j] = (byz[j] ^ ux) & TMASK;
        // aligned 16B pair containing entry ia[j] (and, if x even, also ia[j]^1)
        pr[j] = *(const floatx4*)(tbl_f + (size_t)(ia[j] & ~1u) * 2);
    }

    floatx2 f0[4], f1[4];
    #pragma unroll
    for (int j = 0; j < 4; ++j) {
        const floatx2 lo = { pr[j].x, pr[j].y };
        const floatx2 hi = { pr[j].z, pr[j].w };
        const bool odd_entry = (ia[j] & 1u) != 0u;
        f0[j] = odd_entry ? hi : lo;      // entry ia[j]       (corner x)
        f1[j] = odd_entry ? lo : hi;      // entry ia[j]^1     (= corner x+1 iff x even)
    }

    if (ux & 1u) {                         // x odd: corner x+1 needs its own gather
        const uint32_t ux1 = ux + 1u;
        #pragma unroll
        for (int j = 0; j < 4; ++j) {
            const uint32_t ib = (byz[j] ^ ux1) & TMASK;
            f1[j] = *(const floatx2*)(tbl_f + (size_t)ib * 2);
        }
    }

    const float gx = 1.f - fx, gy = 1.f - fy, gz = 1.f - fz;
    const float wyv[2] = {gy, fy};
    const float wzv[2] = {gz, fz};

    // identical FMA order to the verified kernel: c = 0..7, c = x*4 + y*2 + z
    float s0 = 0.f, s1 = 0.f;
    #pragma unroll
    for (int j = 0; j < 4; ++j) {
        const float w = (gx * wyv[(j >> 1) & 1]) * wzv[j & 1];
        s0 = fmaf(w, f0[j].x, s0);
        s1 = fmaf(w, f0[j].y, s1);
    }
    #pragma unroll
    for (int j = 0; j < 4; ++j) {
        const float w = (fx * wyv[(j >> 1) & 1]) * wzv[j & 1];
        s0 = fmaf(w, f1[j].x, s0);
        s1 = fmaf(w, f1[j].y, s1);
    }
    floatx2 r = {s0, s1};
    return r;
}

// ---- phase 1: one level per XCD (level = base + blockIdx%8), ws[l][N][2] ----
// R2 lesson: batching 32 gathers in flight was null (-6%) -> request-throughput
// bound, not latency bound. Keep the simple per-point loop (R1 structure).
__global__ __launch_bounds__(BLOCK1) void level_kernel(
    const float* __restrict__ x,
    const float* __restrict__ bb,
    const float* __restrict__ table_f,
    float* __restrict__ ws,
    int n, int level_base)
{
    const int level = level_base + (int)(blockIdx.x & 7);
    const int chunk = (int)(blockIdx.x >> 3);
    const int base  = chunk * CHUNK1 + (int)threadIdx.x;

    const float bx0 = bb[0], by0 = bb[1], bz0 = bb[2];
    const float bx1 = bb[3], by1 = bb[4], bz1 = bb[5];

    const float res = (float)(16 << level);      // floor(16*2^l) exact
    const float* __restrict__ tbl =
        table_f + (((size_t)level << LOG2_T) * 2);
    floatx2* __restrict__ wrow = (floatx2*)ws + (size_t)level * n;

    #pragma unroll
    for (int k = 0; k < PTS1; ++k) {
        const int p = base + k * BLOCK1;
        if (p >= n) continue;
        const float xn = (x[3 * p + 0] - bx0) / (bx1 - bx0);
        const float yn = (x[3 * p + 1] - by0) / (by1 - by0);
        const float zn = (x[3 * p + 2] - bz0) / (bz1 - bz0);
        floatx2 r = encode_point_level(xn, yn, zn, res, tbl);
        // non-temporal: don't evict the resident table from L2
        __builtin_nontemporal_store(r, wrow + p);
    }
}

// ---- phase 2: transpose ws[16][N][2] -> enc[N][32] via LDS, compute mask ----
// (R1 win: LDS-staged contiguous stores removed 3x HBM write amplification;
//  transpose now ~25us. Do not revert to per-lane strided NT stores.)
__global__ __launch_bounds__(256) void transpose_kernel(
    const float* __restrict__ ws,
    const float* __restrict__ x,
    const float* __restrict__ bb,
    float* __restrict__ enc_out,
    float* __restrict__ mask_out,
    int n)
{
    __shared__ float tile[256 * 33];

    const int tid = (int)threadIdx.x;
    const int b0  = (int)blockIdx.x * 256;
    const int p   = b0 + tid;

    const floatx2* __restrict__ w = (const floatx2*)ws;

    if (p < n) {
        float* row = tile + tid * 33;
        #pragma unroll
        for (int l = 0; l < NLEV; ++l) {
            floatx2 v = w[(size_t)l * n + p];     // lane-contiguous: coalesced
            row[2 * l + 0] = v.x;
            row[2 * l + 1] = v.y;
        }

        const float bx0 = bb[0], by0 = bb[1], bz0 = bb[2];
        const float bx1 = bb[3], by1 = bb[4], bz1 = bb[5];
        const float xn = (x[3 * p + 0] - bx0) / (bx1 - bx0);
        const float yn = (x[3 * p + 1] - by0) / (by1 - by0);
        const float zn = (x[3 * p + 2] - bz0) / (bz1 - bz0);
        const bool inb = (xn > 0.f) & (xn < 1.f) &
                         (yn > 0.f) & (yn < 1.f) &
                         (zn > 0.f) & (zn < 1.f);
        __builtin_nontemporal_store(inb ? 1.0f : 0.0f, mask_out + p);
    }
    __syncthreads();

    const int npts = (n - b0 < 256) ? (n - b0) : 256;
    floatx4* const eb = (floatx4*)(enc_out + (size_t)b0 * (2 * NLEV));

    if (npts == 256) {
        #pragma unroll
        for (int it = 0; it < 8; ++it) {
            const int c  = it * 256 + tid;        // float4 chunk within block tile
            const int pp = c >> 3;                // point within block
            const int jj = (c & 7) << 2;          // feature word
            const float* s = tile + pp * 33 + jj;
            floatx4 v = { s[0], s[1], s[2], s[3] };
            __builtin_nontemporal_store(v, eb + c);   // lanes contiguous: 1KiB/wave
        }
    } else {
        for (int it = 0; it < 8; ++it) {
            const int c  = it * 256 + tid;
            const int pp = c >> 3;
            if (pp < npts) {
                const int jj = (c & 7) << 2;
                const float* s = tile + pp * 33 + jj;
                floatx4 v = { s[0], s[1], s[2], s[3] };
                __builtin_nontemporal_store(v, eb + c);
            }
        }
    }
}

// ---- fallback: direct single-kernel version (verified correct) ----
__global__ __launch_bounds__(256) void hashenc_direct(
    const float* __restrict__ x,
    const float* __restrict__ bb,
    const float* __restrict__ table_f,
    float* __restrict__ enc_out,
    float* __restrict__ mask_out,
    int n)
{
    const int i = blockIdx.x * 256 + (int)threadIdx.x;
    if (i >= n) return;

    const float bx0 = bb[0], by0 = bb[1], bz0 = bb[2];
    const float bx1 = bb[3], by1 = bb[4], bz1 = bb[5];
    const float xn = (x[3 * i + 0] - bx0) / (bx1 - bx0);
    const float yn = (x[3 * i + 1] - by0) / (by1 - by0);
    const float zn = (x[3 * i + 2] - bz0) / (bz1 - bz0);
    const bool inb = (xn > 0.f) & (xn < 1.f) &
                     (yn > 0.f) & (yn < 1.f) &
                     (zn > 0.f) & (zn < 1.f);

    float enc[2 * NLEV];
    for (int l = 0; l < NLEV; ++l) {
        const float res = (float)(16 << l);
        floatx2 r = encode_point_level(xn, yn, zn, res,
                                       table_f + (((size_t)l << LOG2_T) * 2));
        enc[2 * l + 0] = r.x;
        enc[2 * l + 1] = r.y;
    }
    floatx4* o = (floatx4*)(enc_out + (size_t)i * (2 * NLEV));
    #pragma unroll
    for (int k = 0; k < (2 * NLEV) / 4; ++k) {
        floatx4 v = { enc[4 * k + 0], enc[4 * k + 1],
                      enc[4 * k + 2], enc[4 * k + 3] };
        __builtin_nontemporal_store(v, o + k);
    }
    __builtin_nontemporal_store(inb ? 1.0f : 0.0f, mask_out + i);
}

extern "C" void kernel_launch(void* const* d_in, const int* in_sizes, int n_in,
                              void* d_out, int out_size, void* d_ws, size_t ws_size,
                              hipStream_t stream) {
    const float* x     = (const float*)d_in[0];
    const float* bb    = (const float*)d_in[1];
    const float* table = (const float*)d_in[2];
    const int n = in_sizes[0] / 3;

    float* enc_out  = (float*)d_out;
    float* mask_out = enc_out + (size_t)n * (2 * NLEV);

    const size_t ws_need = (size_t)NLEV * (size_t)n * 2 * sizeof(float);
    if (ws_size >= ws_need) {
        float* ws = (float*)d_ws;
        const int chunks = (n + CHUNK1 - 1) / CHUNK1;
        const int grid1 = chunks * 8;
        level_kernel<<<grid1, BLOCK1, 0, stream>>>(x, bb, table, ws, n, 0);
        level_kernel<<<grid1, BLOCK1, 0, stream>>>(x, bb, table, ws, n, 8);
        const int grid2 = (n + 255) / 256;
        transpose_kernel<<<grid2, 256, 0, stream>>>(ws, x, bb, enc_out, mask_out, n);
    } else {
        const int grid = (n + 255) / 256;
        hashenc_direct<<<grid, 256, 0, stream>>>(x, bb, table, enc_out, mask_out, n);
    }
}